// Round 19
// baseline (525.010 us; speedup 1.0000x reference)
//
#include <hip/hip_runtime.h>

// MDDNet GNN layer — round 19: fuse aggregate into node_mlp1.
// R18: edge 166µs, aggregate ~70µs standalone (pure 327MB m2 read, serial).
// node_mlp1_fused sums each node's contiguous dst-sorted m2 rows during its
// LDS staging phase (one wave per node, coalesced 1KB rows), overlapping the
// read with MFMA across blocks; aggrb roundtrip + launch deleted.
// N=20000, E=320000, D=128, H1=256, H2=512, H3=1024, K3=640.

constexpr int D  = 128;
constexpr int H1 = 256;
constexpr int H2 = 512;
constexpr int H3 = 1024;
constexpr int K3 = D + H2;   // 640

typedef short  bf16x8 __attribute__((ext_vector_type(8)));
typedef ushort u16x8  __attribute__((ext_vector_type(8)));
typedef float  f32x4  __attribute__((ext_vector_type(4)));

__device__ __forceinline__ float leaky(float x) { return x >= 0.f ? x : 0.01f * x; }

__device__ __forceinline__ ushort f2bf(float f) {
    unsigned u = __float_as_uint(f);
    u += 0x7FFFu + ((u >> 16) & 1u);
    return (ushort)(u >> 16);
}

__device__ __forceinline__ float bf2f(ushort u) {
    return __uint_as_float(((unsigned)u) << 16);
}

__device__ __forceinline__ int swz(int row, int bytecol) {
    return bytecol ^ ((row & 7) << 4);
}

__device__ __forceinline__ f32x4 mfma16(bf16x8 a, bf16x8 b, f32x4 c) {
    return __builtin_amdgcn_mfma_f32_16x16x32_bf16(a, b, c, 0, 0, 0);
}

__device__ __forceinline__ void gload_lds16(const void* g, void* l) {
    __builtin_amdgcn_global_load_lds(
        (const __attribute__((address_space(1))) void*)g,
        (__attribute__((address_space(3))) void*)l, 16, 0, 0);
}

// ---------------------------------------------------------------------------
// Counting sort by dst. scan emits preserved row_start[N+1].
// ---------------------------------------------------------------------------
__global__ __launch_bounds__(256) void hist_kernel(
    const int* __restrict__ dst, int* __restrict__ cursor, int E)
{
    const int i = blockIdx.x * 256 + threadIdx.x;
    if (i < E) atomicAdd(&cursor[dst[i]], 1);
}

__global__ __launch_bounds__(1024) void scan_kernel(
    int* __restrict__ cursor, int* __restrict__ row_start, int n)
{
    __shared__ int sums[1024];
    const int tid  = threadIdx.x;
    const int base = tid * 20;
    int v[20];
    int s = 0;
    #pragma unroll
    for (int i = 0; i < 20; ++i) {
        const int idx = base + i;
        v[i] = (idx < n) ? cursor[idx] : 0;
        s += v[i];
    }
    sums[tid] = s;
    __syncthreads();
    int acc = s;
    for (int d = 1; d < 1024; d <<= 1) {
        const int t = (tid >= d) ? sums[tid - d] : 0;
        __syncthreads();
        acc += t;
        sums[tid] = acc;
        __syncthreads();
    }
    int run = acc - s;
    #pragma unroll
    for (int i = 0; i < 20; ++i) {
        const int idx = base + i;
        if (idx < n) { cursor[idx] = run; row_start[idx] = run; }
        run += v[i];
    }
    if (tid == 1023) row_start[n] = acc;
}

__global__ __launch_bounds__(256) void scatter_kernel(
    const int* __restrict__ src, const int* __restrict__ dst,
    int* __restrict__ cursor, int* __restrict__ se, int* __restrict__ pe,
    int E)
{
    const int i = blockIdx.x * 256 + threadIdx.x;
    if (i < E) {
        const int d   = dst[i];
        const int pos = atomicAdd(&cursor[d], 1);
        se[pos] = src[i];
        pe[pos] = i;
    }
}

// ---------------------------------------------------------------------------
// gather_t: t[pos] = bf16(x0[se[pos]] * ea[pe[pos]]), pre-swizzled chunks.
// ---------------------------------------------------------------------------
__global__ __launch_bounds__(256) void gather_t(
    const float* __restrict__ x0, const float* __restrict__ ea,
    const int* __restrict__ se, const int* __restrict__ pe,
    ushort* __restrict__ t)
{
    const int gid  = blockIdx.x * 256 + threadIdx.x;
    const int e    = gid >> 4;
    const int slot = gid & 15;
    const int s = se[e];
    const int p = pe[e];
    const float4* xp = (const float4*)(x0 + (size_t)s * D + slot * 8);
    const float4* gp = (const float4*)(ea + (size_t)p * D + slot * 8);
    const float4 xa = xp[0], xb = xp[1];
    const float4 ga = gp[0], gb = gp[1];
    u16x8 u;
    u[0] = f2bf(xa.x * ga.x); u[1] = f2bf(xa.y * ga.y);
    u[2] = f2bf(xa.z * ga.z); u[3] = f2bf(xa.w * ga.w);
    u[4] = f2bf(xb.x * gb.x); u[5] = f2bf(xb.y * gb.y);
    u[6] = f2bf(xb.z * gb.z); u[7] = f2bf(xb.w * gb.w);
    const int slot_w = slot ^ (e & 7);
    *(u16x8*)(t + (size_t)e * D + slot_w * 8) = u;
}

// ---------------------------------------------------------------------------
// Pack fp32 W[K][Nc] into bf16 B-fragment tile order.
// ---------------------------------------------------------------------------
__global__ __launch_bounds__(256) void pack_weights(
    const float* __restrict__ W, ushort* __restrict__ Wp, int K, int Nc)
{
    const int KT    = K >> 5;
    const int total = (Nc >> 4) * KT * 64;
    const int idx   = blockIdx.x * 256 + threadIdx.x;
    if (idx >= total) return;
    const int l   = idx & 63;
    const int tt  = idx >> 6;
    const int ks  = tt % KT;
    const int ni  = tt / KT;
    const int col = ni * 16 + (l & 15);
    const int k0  = ks * 32 + (l >> 4) * 8;
    u16x8 u;
    #pragma unroll
    for (int j = 0; j < 8; ++j) u[j] = f2bf(W[(size_t)(k0 + j) * Nc + col]);
    *(u16x8*)(Wp + (size_t)idx * 8) = u;
}

// ---------------------------------------------------------------------------
// Pure dense edge MLP (unchanged from R18): stage t -> GEMM1 -> GEMM2 ->
// LDS-staged coalesced u16x8 stores of m2[E][512].
// ---------------------------------------------------------------------------
constexpr int TE = 64;

__global__ __launch_bounds__(512) void edge_mlp_dense(
    const ushort* __restrict__ t,
    const ushort* __restrict__ W1p, const float* __restrict__ b1,
    const ushort* __restrict__ W2p, const float* __restrict__ b2,
    ushort* __restrict__ m2)
{
    __shared__ __align__(16) ushort t_lds[TE * D];      // 16 KB
    __shared__ __align__(16) ushort m1_lds[TE * H1];    // 32 KB
    __shared__ __align__(16) ushort m2_lds[TE * 256];   // 32 KB

    const int tid  = threadIdx.x;
    const int e0   = blockIdx.x * TE;
    const int lane = tid & 63;
    const int w    = tid >> 6;     // 0..7
    const int lr   = lane & 15;
    const int lg   = lane >> 4;

    const ushort* gsrc = t + (size_t)e0 * D;
    #pragma unroll
    for (int i = 0; i < 2; ++i) {
        const int c = (w * 2 + i) * 64 + lane;
        gload_lds16(gsrc + (size_t)c * 8, t_lds + (w * 2 + i) * 512);
    }
    __syncthreads();

    // ---- GEMM1: m1[64][256] = leaky(t @ W1 + b1)
    {
        f32x4 acc[4][2];
        #pragma unroll
        for (int ntl = 0; ntl < 2; ++ntl) {
            const float b = b1[(w * 2 + ntl) * 16 + lr];
            #pragma unroll
            for (int mt = 0; mt < 4; ++mt) acc[mt][ntl] = (f32x4){b, b, b, b};
        }
        #pragma unroll
        for (int ks = 0; ks < 4; ++ks) {
            bf16x8 af[4];
            #pragma unroll
            for (int mt = 0; mt < 4; ++mt) {
                const int row = mt * 16 + lr;
                af[mt] = *(const bf16x8*)((const char*)t_lds + row * 256 +
                                          swz(row, ks * 64 + lg * 16));
            }
            #pragma unroll
            for (int ntl = 0; ntl < 2; ++ntl) {
                const bf16x8 bf = *(const bf16x8*)(W1p +
                    ((size_t)((w * 2 + ntl) * 4 + ks) * 64 + lane) * 8);
                #pragma unroll
                for (int mt = 0; mt < 4; ++mt)
                    acc[mt][ntl] = mfma16(af[mt], bf, acc[mt][ntl]);
            }
        }
        #pragma unroll
        for (int mt = 0; mt < 4; ++mt)
            #pragma unroll
            for (int ntl = 0; ntl < 2; ++ntl)
                #pragma unroll
                for (int r = 0; r < 4; ++r) {
                    const int row = mt * 16 + lg * 4 + r;
                    const int col = (w * 2 + ntl) * 16 + lr;
                    *(ushort*)((char*)m1_lds + row * 512 + swz(row, col * 2)) =
                        f2bf(leaky(acc[mt][ntl][r]));
                }
    }
    __syncthreads();

    // ---- GEMM2: two 256-col passes, LDS-staged coalesced stores
    #pragma unroll
    for (int p = 0; p < 2; ++p) {
        f32x4 acc[4][2];
        #pragma unroll
        for (int ntl = 0; ntl < 2; ++ntl) {
            const int nt = p * 16 + w * 2 + ntl;
            const float b = b2[nt * 16 + lr];
            #pragma unroll
            for (int mt = 0; mt < 4; ++mt) acc[mt][ntl] = (f32x4){b, b, b, b};
        }
        #pragma unroll
        for (int ks = 0; ks < 8; ++ks) {
            bf16x8 af[4];
            #pragma unroll
            for (int mt = 0; mt < 4; ++mt) {
                const int row = mt * 16 + lr;
                af[mt] = *(const bf16x8*)((const char*)m1_lds + row * 512 +
                                          swz(row, ks * 64 + lg * 16));
            }
            #pragma unroll
            for (int ntl = 0; ntl < 2; ++ntl) {
                const int nt = p * 16 + w * 2 + ntl;
                const bf16x8 bf = *(const bf16x8*)(W2p +
                    ((size_t)(nt * 8 + ks) * 64 + lane) * 8);
                #pragma unroll
                for (int mt = 0; mt < 4; ++mt)
                    acc[mt][ntl] = mfma16(af[mt], bf, acc[mt][ntl]);
            }
        }
        #pragma unroll
        for (int mt = 0; mt < 4; ++mt)
            #pragma unroll
            for (int ntl = 0; ntl < 2; ++ntl)
                #pragma unroll
                for (int r = 0; r < 4; ++r) {
                    const int row = mt * 16 + lg * 4 + r;
                    const int col = (w * 2 + ntl) * 16 + lr;
                    *(ushort*)((char*)m2_lds + row * 512 + swz(row, col * 2)) =
                        f2bf(leaky(acc[mt][ntl][r]));
                }
        __syncthreads();
        #pragma unroll
        for (int i = 0; i < 4; ++i) {
            const int c    = i * 512 + tid;
            const int row  = c >> 5;
            const int col8 = c & 31;
            const u16x8 v = *(const u16x8*)((const char*)m2_lds + row * 512 +
                                            swz(row, col8 * 16));
            *(u16x8*)(m2 + (size_t)(e0 + row) * H2 + p * 256 + col8 * 8) = v;
        }
        __syncthreads();
    }
}

// ---------------------------------------------------------------------------
// node_mlp1_fused: staging sums each node's contiguous m2 rows (aggregate
// fused; one WAVE per node -> no divergence, coalesced 1KB rows), then
// h = bf16(leaky(concat(x0, aggr) @ W3 + b3)). 8 waves, full 1024 cols
// per block (2 groups of 4 ntiles per wave). Grid N/32.
// ---------------------------------------------------------------------------
constexpr int TN = 32;

__global__ __launch_bounds__(512) void node_mlp1_fused(
    const float* __restrict__ x0, const ushort* __restrict__ m2,
    const int* __restrict__ row_start,
    const ushort* __restrict__ W3p, const float* __restrict__ b3,
    ushort* __restrict__ h)
{
    __shared__ __align__(16) ushort a_lds[TN * K3];  // 40 KB
    const int tid  = threadIdx.x;
    const int n0   = blockIdx.x * TN;
    const int lane = tid & 63;
    const int w    = tid >> 6;
    const int lr   = lane & 15;
    const int lg   = lane >> 4;

    // stage x0: 512 chunks (32 rows x 16)
    {
        const int row  = tid >> 4;
        const int slot = tid & 15;
        const float* sp = x0 + (size_t)(n0 + row) * D + slot * 8;
        const float4 va = ((const float4*)sp)[0];
        const float4 vb = ((const float4*)sp)[1];
        u16x8 u;
        u[0] = f2bf(va.x); u[1] = f2bf(va.y); u[2] = f2bf(va.z); u[3] = f2bf(va.w);
        u[4] = f2bf(vb.x); u[5] = f2bf(vb.y); u[6] = f2bf(vb.z); u[7] = f2bf(vb.w);
        *(u16x8*)((char*)a_lds + row * 1280 + swz(row, slot * 16)) = u;
    }
    // stage aggr = sum of m2 rows: 2048 chunk-sums, 4/thread.
    // c layout: row = c>>6 -> each WAVE covers one node (c 64-aligned blocks),
    // 64 lanes read one full 1KB m2 row coalesced per iteration.
    #pragma unroll
    for (int i = 0; i < 4; ++i) {
        const int c    = i * 512 + tid;
        const int row  = c >> 6;      // node 0..31
        const int slot = c & 63;      // 16B chunk within 512 cols
        const int rs0 = row_start[n0 + row];
        const int rs1 = row_start[n0 + row + 1];
        float acc[8];
        #pragma unroll
        for (int j = 0; j < 8; ++j) acc[j] = 0.f;
        for (int e = rs0; e < rs1; ++e) {
            const u16x8 v = *(const u16x8*)(m2 + (size_t)e * H2 + slot * 8);
            #pragma unroll
            for (int j = 0; j < 8; ++j) acc[j] += bf2f(v[j]);
        }
        u16x8 u;
        #pragma unroll
        for (int j = 0; j < 8; ++j) u[j] = f2bf(acc[j]);
        *(u16x8*)((char*)a_lds + row * 1280 + swz(row, (16 + slot) * 16)) = u;
    }
    __syncthreads();

    // GEMM: wave owns 8 of 64 ntiles, 2 groups of 4; 20 ks
    #pragma unroll
    for (int g = 0; g < 2; ++g) {
        f32x4 acc[2][4];
        #pragma unroll
        for (int ntl = 0; ntl < 4; ++ntl) {
            const int colg = (w * 8 + g * 4 + ntl) * 16 + lr;
            const float b = b3[colg];
            #pragma unroll
            for (int mt = 0; mt < 2; ++mt) acc[mt][ntl] = (f32x4){b, b, b, b};
        }
        for (int ks = 0; ks < 20; ++ks) {
            bf16x8 af[2];
            #pragma unroll
            for (int mt = 0; mt < 2; ++mt) {
                const int row = mt * 16 + lr;
                af[mt] = *(const bf16x8*)((const char*)a_lds + row * 1280 +
                                          swz(row, ks * 64 + lg * 16));
            }
            #pragma unroll
            for (int ntl = 0; ntl < 4; ++ntl) {
                const int nt = w * 8 + g * 4 + ntl;
                const bf16x8 bf = *(const bf16x8*)(W3p +
                    ((size_t)(nt * 20 + ks) * 64 + lane) * 8);
                #pragma unroll
                for (int mt = 0; mt < 2; ++mt)
                    acc[mt][ntl] = mfma16(af[mt], bf, acc[mt][ntl]);
            }
        }
        #pragma unroll
        for (int mt = 0; mt < 2; ++mt)
            #pragma unroll
            for (int ntl = 0; ntl < 4; ++ntl) {
                const int colg = (w * 8 + g * 4 + ntl) * 16 + lr;
                #pragma unroll
                for (int r = 0; r < 4; ++r) {
                    const int row = n0 + mt * 16 + lg * 4 + r;
                    h[(size_t)row * H3 + colg] = f2bf(leaky(acc[mt][ntl][r]));
                }
            }
    }
}

// ---------------------------------------------------------------------------
// out = ((h @ W4 + b4)·BN + x0) / 2
// ---------------------------------------------------------------------------
__global__ __launch_bounds__(256) void node_mlp2_mfma(
    const ushort* __restrict__ h, const float* __restrict__ x0,
    const ushort* __restrict__ W4p, const float* __restrict__ b4,
    const float* __restrict__ gamma, const float* __restrict__ beta,
    const float* __restrict__ mean, const float* __restrict__ var,
    float* __restrict__ out)
{
    const int tid  = threadIdx.x;
    const int n0   = blockIdx.x * TN;
    const int lane = tid & 63;
    const int w    = tid >> 6;
    const int lr   = lane & 15;
    const int lg   = lane >> 4;

    f32x4 acc[2][2];
    #pragma unroll
    for (int ntl = 0; ntl < 2; ++ntl) {
        const float b = b4[(w * 2 + ntl) * 16 + lr];
        #pragma unroll
        for (int mt = 0; mt < 2; ++mt) acc[mt][ntl] = (f32x4){b, b, b, b};
    }
    for (int ks = 0; ks < 32; ++ks) {
        bf16x8 af[2];
        #pragma unroll
        for (int mt = 0; mt < 2; ++mt)
            af[mt] = *(const bf16x8*)(h + (size_t)(n0 + mt * 16 + lr) * H3 +
                                      ks * 32 + lg * 8);
        #pragma unroll
        for (int ntl = 0; ntl < 2; ++ntl) {
            const bf16x8 bf = *(const bf16x8*)(W4p +
                ((size_t)((w * 2 + ntl) * 32 + ks) * 64 + lane) * 8);
            #pragma unroll
            for (int mt = 0; mt < 2; ++mt)
                acc[mt][ntl] = mfma16(af[mt], bf, acc[mt][ntl]);
        }
    }
    #pragma unroll
    for (int ntl = 0; ntl < 2; ++ntl) {
        const int col = (w * 2 + ntl) * 16 + lr;
        const float sc = gamma[col] * rsqrtf(var[col] + 1e-5f);
        const float bo = beta[col] - mean[col] * sc;
        #pragma unroll
        for (int mt = 0; mt < 2; ++mt)
            #pragma unroll
            for (int r = 0; r < 4; ++r) {
                const int row = n0 + mt * 16 + lg * 4 + r;
                const float v = acc[mt][ntl][r] * sc + bo;
                out[(size_t)row * D + col] =
                    0.5f * (v + x0[(size_t)row * D + col]);
            }
    }
}

extern "C" void kernel_launch(void* const* d_in, const int* in_sizes, int n_in,
                              void* d_out, int out_size, void* d_ws, size_t ws_size,
                              hipStream_t stream)
{
    const float* x0    = (const float*)d_in[0];
    const int*   ei    = (const int*)d_in[1];
    const float* ea    = (const float*)d_in[2];
    const float* W1    = (const float*)d_in[3];
    const float* b1    = (const float*)d_in[4];
    const float* W2    = (const float*)d_in[5];
    const float* b2    = (const float*)d_in[6];
    const float* W3    = (const float*)d_in[7];
    const float* b3    = (const float*)d_in[8];
    const float* W4    = (const float*)d_in[9];
    const float* b4    = (const float*)d_in[10];
    const float* gamma = (const float*)d_in[11];
    const float* beta  = (const float*)d_in[12];
    const float* mean  = (const float*)d_in[13];
    const float* var   = (const float*)d_in[14];
    float* out = (float*)d_out;

    const int N = in_sizes[0] / D;   // 20000
    const int E = in_sizes[2] / D;   // 320000
    const int* src = ei;
    const int* dst = ei + E;

    // workspace (~415 MB):
    //   t     bf16[E*128]  81.9 MB   (h bf16[N*1024]=41MB aliases t)
    //   m2    bf16[E*512] 327.7 MB
    //   sort ints + packed weights ~4.6 MB
    char* ws = (char*)d_ws;
    ushort* t  = (ushort*)ws;
    ushort* h  = t;   // alias: mlp1 writes h AFTER edge kernel consumed t
    ushort* m2 = t + (size_t)E * D;
    char*   p2 = (char*)(m2 + (size_t)E * H2);
    int* cursor    = (int*)p2;           // N
    int* row_start = cursor + N;         // N+1
    int* se        = row_start + N + 1;  // E
    int* pe        = se + E;             // E
    ushort* W1p = (ushort*)(pe + E);
    ushort* W2p = W1p + (size_t)(D  / 32) * (H1 / 16) * 512;
    ushort* W3p = W2p + (size_t)(H1 / 32) * (H2 / 16) * 512;
    ushort* W4p = W3p + (size_t)(K3 / 32) * (H3 / 16) * 512;

    hipMemsetAsync(cursor, 0, (size_t)N * sizeof(int), stream);

    pack_weights<<<(4096  + 255) / 256, 256, 0, stream>>>(W1, W1p, D,  H1);
    pack_weights<<<(16384 + 255) / 256, 256, 0, stream>>>(W2, W2p, H1, H2);
    pack_weights<<<(81920 + 255) / 256, 256, 0, stream>>>(W3, W3p, K3, H3);
    pack_weights<<<(16384 + 255) / 256, 256, 0, stream>>>(W4, W4p, H3, D);

    hist_kernel<<<(E + 255) / 256, 256, 0, stream>>>(dst, cursor, E);
    scan_kernel<<<1, 1024, 0, stream>>>(cursor, row_start, N);
    scatter_kernel<<<(E + 255) / 256, 256, 0, stream>>>(src, dst, cursor,
                                                        se, pe, E);

    gather_t<<<E / 16, 256, 0, stream>>>(x0, ea, se, pe, t);
    edge_mlp_dense<<<E / TE, 512, 0, stream>>>(t, W1p, b1, W2p, b2, m2);

    node_mlp1_fused<<<N / TN, 512, 0, stream>>>(x0, m2, row_start, W3p, b3, h);
    node_mlp2_mfma<<<N / TN, 256, 0, stream>>>(h, x0, W4p, b4, gamma, beta, mean, var, out);
}

// Round 20
// 481.453 us; speedup vs baseline: 1.0905x; 1.0905x over previous
//
#include <hip/hip_runtime.h>

// MDDNet GNN layer — round 20: revert to R18 (best, 488µs) after R19's
// fusion falsifier hit (fused mlp1 218µs: barrier blocks GEMM behind the
// slowest wave's degree-loop; separate 20000-wave aggregate hides latency).
// Single change vs R18: the four pack_weights launches fused into one.
// N=20000, E=320000, D=128, H1=256, H2=512, H3=1024, K3=640.

constexpr int D  = 128;
constexpr int H1 = 256;
constexpr int H2 = 512;
constexpr int H3 = 1024;
constexpr int K3 = D + H2;   // 640

typedef short  bf16x8 __attribute__((ext_vector_type(8)));
typedef ushort u16x8  __attribute__((ext_vector_type(8)));
typedef float  f32x4  __attribute__((ext_vector_type(4)));

__device__ __forceinline__ float leaky(float x) { return x >= 0.f ? x : 0.01f * x; }

__device__ __forceinline__ ushort f2bf(float f) {
    unsigned u = __float_as_uint(f);
    u += 0x7FFFu + ((u >> 16) & 1u);
    return (ushort)(u >> 16);
}

__device__ __forceinline__ float bf2f(ushort u) {
    return __uint_as_float(((unsigned)u) << 16);
}

__device__ __forceinline__ int swz(int row, int bytecol) {
    return bytecol ^ ((row & 7) << 4);
}

__device__ __forceinline__ f32x4 mfma16(bf16x8 a, bf16x8 b, f32x4 c) {
    return __builtin_amdgcn_mfma_f32_16x16x32_bf16(a, b, c, 0, 0, 0);
}

__device__ __forceinline__ void gload_lds16(const void* g, void* l) {
    __builtin_amdgcn_global_load_lds(
        (const __attribute__((address_space(1))) void*)g,
        (__attribute__((address_space(3))) void*)l, 16, 0, 0);
}

// ---------------------------------------------------------------------------
// Counting sort by dst. scan emits preserved row_start[N+1].
// ---------------------------------------------------------------------------
__global__ __launch_bounds__(256) void hist_kernel(
    const int* __restrict__ dst, int* __restrict__ cursor, int E)
{
    const int i = blockIdx.x * 256 + threadIdx.x;
    if (i < E) atomicAdd(&cursor[dst[i]], 1);
}

__global__ __launch_bounds__(1024) void scan_kernel(
    int* __restrict__ cursor, int* __restrict__ row_start, int n)
{
    __shared__ int sums[1024];
    const int tid  = threadIdx.x;
    const int base = tid * 20;
    int v[20];
    int s = 0;
    #pragma unroll
    for (int i = 0; i < 20; ++i) {
        const int idx = base + i;
        v[i] = (idx < n) ? cursor[idx] : 0;
        s += v[i];
    }
    sums[tid] = s;
    __syncthreads();
    int acc = s;
    for (int d = 1; d < 1024; d <<= 1) {
        const int t = (tid >= d) ? sums[tid - d] : 0;
        __syncthreads();
        acc += t;
        sums[tid] = acc;
        __syncthreads();
    }
    int run = acc - s;
    #pragma unroll
    for (int i = 0; i < 20; ++i) {
        const int idx = base + i;
        if (idx < n) { cursor[idx] = run; row_start[idx] = run; }
        run += v[i];
    }
    if (tid == 1023) row_start[n] = acc;
}

__global__ __launch_bounds__(256) void scatter_kernel(
    const int* __restrict__ src, const int* __restrict__ dst,
    int* __restrict__ cursor, int* __restrict__ se, int* __restrict__ pe,
    int E)
{
    const int i = blockIdx.x * 256 + threadIdx.x;
    if (i < E) {
        const int d   = dst[i];
        const int pos = atomicAdd(&cursor[d], 1);
        se[pos] = src[i];
        pe[pos] = i;
    }
}

// ---------------------------------------------------------------------------
// gather_t: t[pos] = bf16(x0[se[pos]] * ea[pe[pos]]), pre-swizzled chunks.
// ---------------------------------------------------------------------------
__global__ __launch_bounds__(256) void gather_t(
    const float* __restrict__ x0, const float* __restrict__ ea,
    const int* __restrict__ se, const int* __restrict__ pe,
    ushort* __restrict__ t)
{
    const int gid  = blockIdx.x * 256 + threadIdx.x;
    const int e    = gid >> 4;
    const int slot = gid & 15;
    const int s = se[e];
    const int p = pe[e];
    const float4* xp = (const float4*)(x0 + (size_t)s * D + slot * 8);
    const float4* gp = (const float4*)(ea + (size_t)p * D + slot * 8);
    const float4 xa = xp[0], xb = xp[1];
    const float4 ga = gp[0], gb = gp[1];
    u16x8 u;
    u[0] = f2bf(xa.x * ga.x); u[1] = f2bf(xa.y * ga.y);
    u[2] = f2bf(xa.z * ga.z); u[3] = f2bf(xa.w * ga.w);
    u[4] = f2bf(xb.x * gb.x); u[5] = f2bf(xb.y * gb.y);
    u[6] = f2bf(xb.z * gb.z); u[7] = f2bf(xb.w * gb.w);
    const int slot_w = slot ^ (e & 7);
    *(u16x8*)(t + (size_t)e * D + slot_w * 8) = u;
}

// ---------------------------------------------------------------------------
// Fused weight pack: all four W matrices in one launch. Segment decoded by
// flat chunk index; same per-chunk layout math as before.
// ---------------------------------------------------------------------------
__global__ __launch_bounds__(256) void pack_all_weights(
    const float* __restrict__ W1, const float* __restrict__ W2,
    const float* __restrict__ W3, const float* __restrict__ W4,
    ushort* __restrict__ W1p, ushort* __restrict__ W2p,
    ushort* __restrict__ W3p, ushort* __restrict__ W4p)
{
    // chunk counts: W1 4096, W2 16384, W3 81920, W4 16384  (total 118784)
    int idx = blockIdx.x * 256 + threadIdx.x;
    const float* W; ushort* Wp; int K, Nc;
    if (idx < 4096)        { W = W1; Wp = W1p; K = D;  Nc = H1; }
    else if (idx < 20480)  { W = W2; Wp = W2p; K = H1; Nc = H2; idx -= 4096; }
    else if (idx < 102400) { W = W3; Wp = W3p; K = K3; Nc = H3; idx -= 20480; }
    else if (idx < 118784) { W = W4; Wp = W4p; K = H3; Nc = D;  idx -= 102400; }
    else return;

    const int KT  = K >> 5;
    const int l   = idx & 63;
    const int tt  = idx >> 6;
    const int ks  = tt % KT;
    const int ni  = tt / KT;
    const int col = ni * 16 + (l & 15);
    const int k0  = ks * 32 + (l >> 4) * 8;
    u16x8 u;
    #pragma unroll
    for (int j = 0; j < 8; ++j) u[j] = f2bf(W[(size_t)(k0 + j) * Nc + col]);
    *(u16x8*)(Wp + (size_t)idx * 8) = u;
}

// ---------------------------------------------------------------------------
// Pure dense edge MLP: stage t -> GEMM1 (m1 in LDS) -> GEMM2 (two 256-col
// passes) -> m2 pass staged in LDS -> coalesced u16x8 stores.
// TE=64, 512 threads, 8 waves, LDS 80.5KB.
// ---------------------------------------------------------------------------
constexpr int TE = 64;

__global__ __launch_bounds__(512) void edge_mlp_dense(
    const ushort* __restrict__ t,
    const ushort* __restrict__ W1p, const float* __restrict__ b1,
    const ushort* __restrict__ W2p, const float* __restrict__ b2,
    ushort* __restrict__ m2)
{
    __shared__ __align__(16) ushort t_lds[TE * D];      // 16 KB
    __shared__ __align__(16) ushort m1_lds[TE * H1];    // 32 KB
    __shared__ __align__(16) ushort m2_lds[TE * 256];   // 32 KB

    const int tid  = threadIdx.x;
    const int e0   = blockIdx.x * TE;
    const int lane = tid & 63;
    const int w    = tid >> 6;     // 0..7
    const int lr   = lane & 15;
    const int lg   = lane >> 4;

    const ushort* gsrc = t + (size_t)e0 * D;
    #pragma unroll
    for (int i = 0; i < 2; ++i) {
        const int c = (w * 2 + i) * 64 + lane;
        gload_lds16(gsrc + (size_t)c * 8, t_lds + (w * 2 + i) * 512);
    }
    __syncthreads();

    // ---- GEMM1: m1[64][256] = leaky(t @ W1 + b1)
    {
        f32x4 acc[4][2];
        #pragma unroll
        for (int ntl = 0; ntl < 2; ++ntl) {
            const float b = b1[(w * 2 + ntl) * 16 + lr];
            #pragma unroll
            for (int mt = 0; mt < 4; ++mt) acc[mt][ntl] = (f32x4){b, b, b, b};
        }
        #pragma unroll
        for (int ks = 0; ks < 4; ++ks) {
            bf16x8 af[4];
            #pragma unroll
            for (int mt = 0; mt < 4; ++mt) {
                const int row = mt * 16 + lr;
                af[mt] = *(const bf16x8*)((const char*)t_lds + row * 256 +
                                          swz(row, ks * 64 + lg * 16));
            }
            #pragma unroll
            for (int ntl = 0; ntl < 2; ++ntl) {
                const bf16x8 bf = *(const bf16x8*)(W1p +
                    ((size_t)((w * 2 + ntl) * 4 + ks) * 64 + lane) * 8);
                #pragma unroll
                for (int mt = 0; mt < 4; ++mt)
                    acc[mt][ntl] = mfma16(af[mt], bf, acc[mt][ntl]);
            }
        }
        #pragma unroll
        for (int mt = 0; mt < 4; ++mt)
            #pragma unroll
            for (int ntl = 0; ntl < 2; ++ntl)
                #pragma unroll
                for (int r = 0; r < 4; ++r) {
                    const int row = mt * 16 + lg * 4 + r;
                    const int col = (w * 2 + ntl) * 16 + lr;
                    *(ushort*)((char*)m1_lds + row * 512 + swz(row, col * 2)) =
                        f2bf(leaky(acc[mt][ntl][r]));
                }
    }
    __syncthreads();

    // ---- GEMM2: two 256-col passes, LDS-staged coalesced stores
    #pragma unroll
    for (int p = 0; p < 2; ++p) {
        f32x4 acc[4][2];
        #pragma unroll
        for (int ntl = 0; ntl < 2; ++ntl) {
            const int nt = p * 16 + w * 2 + ntl;
            const float b = b2[nt * 16 + lr];
            #pragma unroll
            for (int mt = 0; mt < 4; ++mt) acc[mt][ntl] = (f32x4){b, b, b, b};
        }
        #pragma unroll
        for (int ks = 0; ks < 8; ++ks) {
            bf16x8 af[4];
            #pragma unroll
            for (int mt = 0; mt < 4; ++mt) {
                const int row = mt * 16 + lr;
                af[mt] = *(const bf16x8*)((const char*)m1_lds + row * 512 +
                                          swz(row, ks * 64 + lg * 16));
            }
            #pragma unroll
            for (int ntl = 0; ntl < 2; ++ntl) {
                const int nt = p * 16 + w * 2 + ntl;
                const bf16x8 bf = *(const bf16x8*)(W2p +
                    ((size_t)(nt * 8 + ks) * 64 + lane) * 8);
                #pragma unroll
                for (int mt = 0; mt < 4; ++mt)
                    acc[mt][ntl] = mfma16(af[mt], bf, acc[mt][ntl]);
            }
        }
        #pragma unroll
        for (int mt = 0; mt < 4; ++mt)
            #pragma unroll
            for (int ntl = 0; ntl < 2; ++ntl)
                #pragma unroll
                for (int r = 0; r < 4; ++r) {
                    const int row = mt * 16 + lg * 4 + r;
                    const int col = (w * 2 + ntl) * 16 + lr;
                    *(ushort*)((char*)m2_lds + row * 512 + swz(row, col * 2)) =
                        f2bf(leaky(acc[mt][ntl][r]));
                }
        __syncthreads();
        #pragma unroll
        for (int i = 0; i < 4; ++i) {
            const int c    = i * 512 + tid;
            const int row  = c >> 5;
            const int col8 = c & 31;
            const u16x8 v = *(const u16x8*)((const char*)m2_lds + row * 512 +
                                            swz(row, col8 * 16));
            *(u16x8*)(m2 + (size_t)(e0 + row) * H2 + p * 256 + col8 * 8) = v;
        }
        __syncthreads();
    }
}

// ---------------------------------------------------------------------------
// aggregate: wave per node sums its contiguous dst-sorted m2 rows; writes
// aggr in bf16 (node_mlp1 rounds to bf16 anyway -> numerically identical).
// ---------------------------------------------------------------------------
__global__ __launch_bounds__(512) void aggregate_kernel(
    const ushort* __restrict__ m2, const int* __restrict__ row_start,
    ushort* __restrict__ aggrb)
{
    const int lane = threadIdx.x & 63;
    const int w    = threadIdx.x >> 6;
    const int n    = blockIdx.x * 8 + w;

    const int rs0 = row_start[n], rs1 = row_start[n + 1];
    float acc[8];
    #pragma unroll
    for (int j = 0; j < 8; ++j) acc[j] = 0.f;

    for (int e = rs0; e < rs1; ++e) {
        const u16x8 v = *(const u16x8*)(m2 + (size_t)e * H2 + lane * 8);
        #pragma unroll
        for (int j = 0; j < 8; ++j) acc[j] += bf2f(v[j]);
    }

    u16x8 o;
    #pragma unroll
    for (int j = 0; j < 8; ++j) o[j] = f2bf(acc[j]);
    *(u16x8*)(aggrb + (size_t)n * H2 + lane * 8) = o;
}

// ---------------------------------------------------------------------------
// h[N][1024] = bf16(leaky(concat(x0, aggr_bf16) @ W3 + b3)); 8 waves.
// ---------------------------------------------------------------------------
constexpr int TN = 32;

__global__ __launch_bounds__(512) void node_mlp1_mfma(
    const float* __restrict__ x0, const ushort* __restrict__ aggrb,
    const ushort* __restrict__ W3p, const float* __restrict__ b3,
    ushort* __restrict__ h)
{
    __shared__ __align__(16) ushort a_lds[TN * K3];  // 40 KB
    const int tid  = threadIdx.x;
    const int n0   = blockIdx.x * TN;
    const int ch   = blockIdx.y;
    const int lane = tid & 63;
    const int w    = tid >> 6;
    const int lr   = lane & 15;
    const int lg   = lane >> 4;

    #pragma unroll
    for (int i = 0; i < 5; ++i) {
        const int c    = i * 512 + tid;
        const int row  = c / 80;
        const int slot = c % 80;
        u16x8 u;
        if (slot < 16) {
            const float* sp = x0 + (size_t)(n0 + row) * D + slot * 8;
            const float4 va = ((const float4*)sp)[0];
            const float4 vb = ((const float4*)sp)[1];
            u[0] = f2bf(va.x); u[1] = f2bf(va.y); u[2] = f2bf(va.z); u[3] = f2bf(va.w);
            u[4] = f2bf(vb.x); u[5] = f2bf(vb.y); u[6] = f2bf(vb.z); u[7] = f2bf(vb.w);
        } else {
            u = *(const u16x8*)(aggrb + (size_t)(n0 + row) * H2 + (slot - 16) * 8);
        }
        *(u16x8*)((char*)a_lds + row * 1280 + swz(row, slot * 16)) = u;
    }
    __syncthreads();

    f32x4 acc[2][4];
    #pragma unroll
    for (int ntl = 0; ntl < 4; ++ntl) {
        const int colg = ch * 512 + (w * 4 + ntl) * 16 + lr;
        const float b = b3[colg];
        #pragma unroll
        for (int mt = 0; mt < 2; ++mt) acc[mt][ntl] = (f32x4){b, b, b, b};
    }
    for (int ks = 0; ks < 20; ++ks) {
        bf16x8 af[2];
        #pragma unroll
        for (int mt = 0; mt < 2; ++mt) {
            const int row = mt * 16 + lr;
            af[mt] = *(const bf16x8*)((const char*)a_lds + row * 1280 +
                                      swz(row, ks * 64 + lg * 16));
        }
        #pragma unroll
        for (int ntl = 0; ntl < 4; ++ntl) {
            const int nt = ch * 32 + w * 4 + ntl;
            const bf16x8 bf = *(const bf16x8*)(W3p +
                ((size_t)(nt * 20 + ks) * 64 + lane) * 8);
            #pragma unroll
            for (int mt = 0; mt < 2; ++mt)
                acc[mt][ntl] = mfma16(af[mt], bf, acc[mt][ntl]);
        }
    }
    #pragma unroll
    for (int mt = 0; mt < 2; ++mt)
        #pragma unroll
        for (int ntl = 0; ntl < 4; ++ntl) {
            const int colg = ch * 512 + (w * 4 + ntl) * 16 + lr;
            #pragma unroll
            for (int r = 0; r < 4; ++r) {
                const int row = n0 + mt * 16 + lg * 4 + r;
                h[(size_t)row * H3 + colg] = f2bf(leaky(acc[mt][ntl][r]));
            }
        }
}

// ---------------------------------------------------------------------------
// out = ((h @ W4 + b4)·BN + x0) / 2
// ---------------------------------------------------------------------------
__global__ __launch_bounds__(256) void node_mlp2_mfma(
    const ushort* __restrict__ h, const float* __restrict__ x0,
    const ushort* __restrict__ W4p, const float* __restrict__ b4,
    const float* __restrict__ gamma, const float* __restrict__ beta,
    const float* __restrict__ mean, const float* __restrict__ var,
    float* __restrict__ out)
{
    const int tid  = threadIdx.x;
    const int n0   = blockIdx.x * TN;
    const int lane = tid & 63;
    const int w    = tid >> 6;
    const int lr   = lane & 15;
    const int lg   = lane >> 4;

    f32x4 acc[2][2];
    #pragma unroll
    for (int ntl = 0; ntl < 2; ++ntl) {
        const float b = b4[(w * 2 + ntl) * 16 + lr];
        #pragma unroll
        for (int mt = 0; mt < 2; ++mt) acc[mt][ntl] = (f32x4){b, b, b, b};
    }
    for (int ks = 0; ks < 32; ++ks) {
        bf16x8 af[2];
        #pragma unroll
        for (int mt = 0; mt < 2; ++mt)
            af[mt] = *(const bf16x8*)(h + (size_t)(n0 + mt * 16 + lr) * H3 +
                                      ks * 32 + lg * 8);
        #pragma unroll
        for (int ntl = 0; ntl < 2; ++ntl) {
            const bf16x8 bf = *(const bf16x8*)(W4p +
                ((size_t)((w * 2 + ntl) * 32 + ks) * 64 + lane) * 8);
            #pragma unroll
            for (int mt = 0; mt < 2; ++mt)
                acc[mt][ntl] = mfma16(af[mt], bf, acc[mt][ntl]);
        }
    }
    #pragma unroll
    for (int ntl = 0; ntl < 2; ++ntl) {
        const int col = (w * 2 + ntl) * 16 + lr;
        const float sc = gamma[col] * rsqrtf(var[col] + 1e-5f);
        const float bo = beta[col] - mean[col] * sc;
        #pragma unroll
        for (int mt = 0; mt < 2; ++mt)
            #pragma unroll
            for (int r = 0; r < 4; ++r) {
                const int row = n0 + mt * 16 + lg * 4 + r;
                const float v = acc[mt][ntl][r] * sc + bo;
                out[(size_t)row * D + col] =
                    0.5f * (v + x0[(size_t)row * D + col]);
            }
    }
}

extern "C" void kernel_launch(void* const* d_in, const int* in_sizes, int n_in,
                              void* d_out, int out_size, void* d_ws, size_t ws_size,
                              hipStream_t stream)
{
    const float* x0    = (const float*)d_in[0];
    const int*   ei    = (const int*)d_in[1];
    const float* ea    = (const float*)d_in[2];
    const float* W1    = (const float*)d_in[3];
    const float* b1    = (const float*)d_in[4];
    const float* W2    = (const float*)d_in[5];
    const float* b2    = (const float*)d_in[6];
    const float* W3    = (const float*)d_in[7];
    const float* b3    = (const float*)d_in[8];
    const float* W4    = (const float*)d_in[9];
    const float* b4    = (const float*)d_in[10];
    const float* gamma = (const float*)d_in[11];
    const float* beta  = (const float*)d_in[12];
    const float* mean  = (const float*)d_in[13];
    const float* var   = (const float*)d_in[14];
    float* out = (float*)d_out;

    const int N = in_sizes[0] / D;   // 20000
    const int E = in_sizes[2] / D;   // 320000
    const int* src = ei;
    const int* dst = ei + E;

    // workspace (~435 MB):
    //   aggrb bf16[N*512]  20.5 MB
    //   t     bf16[E*128]  81.9 MB   (h bf16[N*1024]=41MB aliases t)
    //   m2    bf16[E*512] 327.7 MB
    //   sort ints + packed weights ~4.6 MB
    char* ws = (char*)d_ws;
    ushort* aggrb = (ushort*)ws;
    ushort* t     = (ushort*)(ws + (size_t)N * H2 * 2);
    ushort* h     = t;   // alias: node_mlp1 writes h AFTER edge kernel consumed t
    ushort* m2    = t + (size_t)E * D;
    char*   p2    = (char*)(m2 + (size_t)E * H2);
    int* cursor    = (int*)p2;           // N
    int* row_start = cursor + N;         // N+1
    int* se        = row_start + N + 1;  // E
    int* pe        = se + E;             // E
    ushort* W1p = (ushort*)(pe + E);
    ushort* W2p = W1p + (size_t)(D  / 32) * (H1 / 16) * 512;
    ushort* W3p = W2p + (size_t)(H1 / 32) * (H2 / 16) * 512;
    ushort* W4p = W3p + (size_t)(K3 / 32) * (H3 / 16) * 512;

    hipMemsetAsync(cursor, 0, (size_t)N * sizeof(int), stream);

    pack_all_weights<<<(118784 + 255) / 256, 256, 0, stream>>>(
        W1, W2, W3, W4, W1p, W2p, W3p, W4p);

    hist_kernel<<<(E + 255) / 256, 256, 0, stream>>>(dst, cursor, E);
    scan_kernel<<<1, 1024, 0, stream>>>(cursor, row_start, N);
    scatter_kernel<<<(E + 255) / 256, 256, 0, stream>>>(src, dst, cursor,
                                                        se, pe, E);

    gather_t<<<E / 16, 256, 0, stream>>>(x0, ea, se, pe, t);
    edge_mlp_dense<<<E / TE, 512, 0, stream>>>(t, W1p, b1, W2p, b2, m2);
    aggregate_kernel<<<N / 8, 512, 0, stream>>>(m2, row_start, aggrb);

    dim3 g1(N / TN, 2);
    node_mlp1_mfma<<<g1, 512, 0, stream>>>(x0, aggrb, W3p, b3, h);
    node_mlp2_mfma<<<N / TN, 256, 0, stream>>>(h, x0, W4p, b4, gamma, beta, mean, var, out);
}

// Round 21
// 452.701 us; speedup vs baseline: 1.1597x; 1.0635x over previous
//
#include <hip/hip_runtime.h>

// MDDNet GNN layer — round 21: fuse gather_t into edge staging.
// R20 best = 481µs. gather_t (~70µs) wrote t[E,128] (82MB) that edge
// immediately re-read. Now edge register-stages bf16(x0[se]*ea[pe]) straight
// into the swizzled t_lds (same math/layout); t buffer + kernel deleted.
// Staging regs die at the first barrier (no GEMM-acc overlap; R4 lesson).
// N=20000, E=320000, D=128, H1=256, H2=512, H3=1024, K3=640.

constexpr int D  = 128;
constexpr int H1 = 256;
constexpr int H2 = 512;
constexpr int H3 = 1024;
constexpr int K3 = D + H2;   // 640

typedef short  bf16x8 __attribute__((ext_vector_type(8)));
typedef ushort u16x8  __attribute__((ext_vector_type(8)));
typedef float  f32x4  __attribute__((ext_vector_type(4)));

__device__ __forceinline__ float leaky(float x) { return x >= 0.f ? x : 0.01f * x; }

__device__ __forceinline__ ushort f2bf(float f) {
    unsigned u = __float_as_uint(f);
    u += 0x7FFFu + ((u >> 16) & 1u);
    return (ushort)(u >> 16);
}

__device__ __forceinline__ float bf2f(ushort u) {
    return __uint_as_float(((unsigned)u) << 16);
}

__device__ __forceinline__ int swz(int row, int bytecol) {
    return bytecol ^ ((row & 7) << 4);
}

__device__ __forceinline__ f32x4 mfma16(bf16x8 a, bf16x8 b, f32x4 c) {
    return __builtin_amdgcn_mfma_f32_16x16x32_bf16(a, b, c, 0, 0, 0);
}

// ---------------------------------------------------------------------------
// Counting sort by dst. scan emits preserved row_start[N+1].
// ---------------------------------------------------------------------------
__global__ __launch_bounds__(256) void hist_kernel(
    const int* __restrict__ dst, int* __restrict__ cursor, int E)
{
    const int i = blockIdx.x * 256 + threadIdx.x;
    if (i < E) atomicAdd(&cursor[dst[i]], 1);
}

__global__ __launch_bounds__(1024) void scan_kernel(
    int* __restrict__ cursor, int* __restrict__ row_start, int n)
{
    __shared__ int sums[1024];
    const int tid  = threadIdx.x;
    const int base = tid * 20;
    int v[20];
    int s = 0;
    #pragma unroll
    for (int i = 0; i < 20; ++i) {
        const int idx = base + i;
        v[i] = (idx < n) ? cursor[idx] : 0;
        s += v[i];
    }
    sums[tid] = s;
    __syncthreads();
    int acc = s;
    for (int d = 1; d < 1024; d <<= 1) {
        const int t = (tid >= d) ? sums[tid - d] : 0;
        __syncthreads();
        acc += t;
        sums[tid] = acc;
        __syncthreads();
    }
    int run = acc - s;
    #pragma unroll
    for (int i = 0; i < 20; ++i) {
        const int idx = base + i;
        if (idx < n) { cursor[idx] = run; row_start[idx] = run; }
        run += v[i];
    }
    if (tid == 1023) row_start[n] = acc;
}

__global__ __launch_bounds__(256) void scatter_kernel(
    const int* __restrict__ src, const int* __restrict__ dst,
    int* __restrict__ cursor, int* __restrict__ se, int* __restrict__ pe,
    int E)
{
    const int i = blockIdx.x * 256 + threadIdx.x;
    if (i < E) {
        const int d   = dst[i];
        const int pos = atomicAdd(&cursor[d], 1);
        se[pos] = src[i];
        pe[pos] = i;
    }
}

// ---------------------------------------------------------------------------
// Fused weight pack: all four W matrices in one launch.
// ---------------------------------------------------------------------------
__global__ __launch_bounds__(256) void pack_all_weights(
    const float* __restrict__ W1, const float* __restrict__ W2,
    const float* __restrict__ W3, const float* __restrict__ W4,
    ushort* __restrict__ W1p, ushort* __restrict__ W2p,
    ushort* __restrict__ W3p, ushort* __restrict__ W4p)
{
    int idx = blockIdx.x * 256 + threadIdx.x;
    const float* W; ushort* Wp; int K, Nc;
    if (idx < 4096)        { W = W1; Wp = W1p; K = D;  Nc = H1; }
    else if (idx < 20480)  { W = W2; Wp = W2p; K = H1; Nc = H2; idx -= 4096; }
    else if (idx < 102400) { W = W3; Wp = W3p; K = K3; Nc = H3; idx -= 20480; }
    else if (idx < 118784) { W = W4; Wp = W4p; K = H3; Nc = D;  idx -= 102400; }
    else return;

    const int KT  = K >> 5;
    const int l   = idx & 63;
    const int tt  = idx >> 6;
    const int ks  = tt % KT;
    const int ni  = tt / KT;
    const int col = ni * 16 + (l & 15);
    const int k0  = ks * 32 + (l >> 4) * 8;
    u16x8 u;
    #pragma unroll
    for (int j = 0; j < 8; ++j) u[j] = f2bf(W[(size_t)(k0 + j) * Nc + col]);
    *(u16x8*)(Wp + (size_t)idx * 8) = u;
}

// ---------------------------------------------------------------------------
// Dense edge MLP with fused gather: stage bf16(x0[se]*ea[pe]) into swizzled
// t_lds (register staging, dies at barrier) -> GEMM1 -> GEMM2 (two 256-col
// passes) -> LDS-staged coalesced u16x8 stores of m2[E][512].
// TE=64, 512 threads, 8 waves, LDS 80.5KB (2 blocks/CU).
// ---------------------------------------------------------------------------
constexpr int TE = 64;

__global__ __launch_bounds__(512) void edge_mlp_dense(
    const float* __restrict__ x0, const float* __restrict__ ea,
    const int* __restrict__ se, const int* __restrict__ pe,
    const ushort* __restrict__ W1p, const float* __restrict__ b1,
    const ushort* __restrict__ W2p, const float* __restrict__ b2,
    ushort* __restrict__ m2)
{
    __shared__ __align__(16) ushort t_lds[TE * D];      // 16 KB
    __shared__ __align__(16) ushort m1_lds[TE * H1];    // 32 KB
    __shared__ __align__(16) ushort m2_lds[TE * 256];   // 32 KB

    const int tid  = threadIdx.x;
    const int e0   = blockIdx.x * TE;
    const int lane = tid & 63;
    const int w    = tid >> 6;     // 0..7
    const int lr   = lane & 15;
    const int lg   = lane >> 4;

    // fused gather staging: 1024 chunks (64 rows x 16), 2 per thread.
    // Registers die at the barrier below.
    #pragma unroll
    for (int i = 0; i < 2; ++i) {
        const int c    = i * 512 + tid;
        const int row  = c >> 4;
        const int slot = c & 15;
        const int s = se[e0 + row];
        const int p = pe[e0 + row];
        const float4* xp = (const float4*)(x0 + (size_t)s * D + slot * 8);
        const float4* gp = (const float4*)(ea + (size_t)p * D + slot * 8);
        const float4 xa = xp[0], xb = xp[1];
        const float4 ga = gp[0], gb = gp[1];
        u16x8 u;
        u[0] = f2bf(xa.x * ga.x); u[1] = f2bf(xa.y * ga.y);
        u[2] = f2bf(xa.z * ga.z); u[3] = f2bf(xa.w * ga.w);
        u[4] = f2bf(xb.x * gb.x); u[5] = f2bf(xb.y * gb.y);
        u[6] = f2bf(xb.z * gb.z); u[7] = f2bf(xb.w * gb.w);
        *(u16x8*)((char*)t_lds + row * 256 + swz(row, slot * 16)) = u;
    }
    __syncthreads();

    // ---- GEMM1: m1[64][256] = leaky(t @ W1 + b1)
    {
        f32x4 acc[4][2];
        #pragma unroll
        for (int ntl = 0; ntl < 2; ++ntl) {
            const float b = b1[(w * 2 + ntl) * 16 + lr];
            #pragma unroll
            for (int mt = 0; mt < 4; ++mt) acc[mt][ntl] = (f32x4){b, b, b, b};
        }
        #pragma unroll
        for (int ks = 0; ks < 4; ++ks) {
            bf16x8 af[4];
            #pragma unroll
            for (int mt = 0; mt < 4; ++mt) {
                const int row = mt * 16 + lr;
                af[mt] = *(const bf16x8*)((const char*)t_lds + row * 256 +
                                          swz(row, ks * 64 + lg * 16));
            }
            #pragma unroll
            for (int ntl = 0; ntl < 2; ++ntl) {
                const bf16x8 bf = *(const bf16x8*)(W1p +
                    ((size_t)((w * 2 + ntl) * 4 + ks) * 64 + lane) * 8);
                #pragma unroll
                for (int mt = 0; mt < 4; ++mt)
                    acc[mt][ntl] = mfma16(af[mt], bf, acc[mt][ntl]);
            }
        }
        #pragma unroll
        for (int mt = 0; mt < 4; ++mt)
            #pragma unroll
            for (int ntl = 0; ntl < 2; ++ntl)
                #pragma unroll
                for (int r = 0; r < 4; ++r) {
                    const int row = mt * 16 + lg * 4 + r;
                    const int col = (w * 2 + ntl) * 16 + lr;
                    *(ushort*)((char*)m1_lds + row * 512 + swz(row, col * 2)) =
                        f2bf(leaky(acc[mt][ntl][r]));
                }
    }
    __syncthreads();

    // ---- GEMM2: two 256-col passes, LDS-staged coalesced stores
    #pragma unroll
    for (int p = 0; p < 2; ++p) {
        f32x4 acc[4][2];
        #pragma unroll
        for (int ntl = 0; ntl < 2; ++ntl) {
            const int nt = p * 16 + w * 2 + ntl;
            const float b = b2[nt * 16 + lr];
            #pragma unroll
            for (int mt = 0; mt < 4; ++mt) acc[mt][ntl] = (f32x4){b, b, b, b};
        }
        #pragma unroll
        for (int ks = 0; ks < 8; ++ks) {
            bf16x8 af[4];
            #pragma unroll
            for (int mt = 0; mt < 4; ++mt) {
                const int row = mt * 16 + lr;
                af[mt] = *(const bf16x8*)((const char*)m1_lds + row * 512 +
                                          swz(row, ks * 64 + lg * 16));
            }
            #pragma unroll
            for (int ntl = 0; ntl < 2; ++ntl) {
                const int nt = p * 16 + w * 2 + ntl;
                const bf16x8 bf = *(const bf16x8*)(W2p +
                    ((size_t)(nt * 8 + ks) * 64 + lane) * 8);
                #pragma unroll
                for (int mt = 0; mt < 4; ++mt)
                    acc[mt][ntl] = mfma16(af[mt], bf, acc[mt][ntl]);
            }
        }
        #pragma unroll
        for (int mt = 0; mt < 4; ++mt)
            #pragma unroll
            for (int ntl = 0; ntl < 2; ++ntl)
                #pragma unroll
                for (int r = 0; r < 4; ++r) {
                    const int row = mt * 16 + lg * 4 + r;
                    const int col = (w * 2 + ntl) * 16 + lr;
                    *(ushort*)((char*)m2_lds + row * 512 + swz(row, col * 2)) =
                        f2bf(leaky(acc[mt][ntl][r]));
                }
        __syncthreads();
        #pragma unroll
        for (int i = 0; i < 4; ++i) {
            const int c    = i * 512 + tid;
            const int row  = c >> 5;
            const int col8 = c & 31;
            const u16x8 v = *(const u16x8*)((const char*)m2_lds + row * 512 +
                                            swz(row, col8 * 16));
            *(u16x8*)(m2 + (size_t)(e0 + row) * H2 + p * 256 + col8 * 8) = v;
        }
        __syncthreads();
    }
}

// ---------------------------------------------------------------------------
// aggregate: wave per node sums its contiguous dst-sorted m2 rows; writes
// aggr in bf16 (node_mlp1 rounds to bf16 anyway -> numerically identical).
// ---------------------------------------------------------------------------
__global__ __launch_bounds__(512) void aggregate_kernel(
    const ushort* __restrict__ m2, const int* __restrict__ row_start,
    ushort* __restrict__ aggrb)
{
    const int lane = threadIdx.x & 63;
    const int w    = threadIdx.x >> 6;
    const int n    = blockIdx.x * 8 + w;

    const int rs0 = row_start[n], rs1 = row_start[n + 1];
    float acc[8];
    #pragma unroll
    for (int j = 0; j < 8; ++j) acc[j] = 0.f;

    for (int e = rs0; e < rs1; ++e) {
        const u16x8 v = *(const u16x8*)(m2 + (size_t)e * H2 + lane * 8);
        #pragma unroll
        for (int j = 0; j < 8; ++j) acc[j] += bf2f(v[j]);
    }

    u16x8 o;
    #pragma unroll
    for (int j = 0; j < 8; ++j) o[j] = f2bf(acc[j]);
    *(u16x8*)(aggrb + (size_t)n * H2 + lane * 8) = o;
}

// ---------------------------------------------------------------------------
// h[N][1024] = bf16(leaky(concat(x0, aggr_bf16) @ W3 + b3)); 8 waves.
// ---------------------------------------------------------------------------
constexpr int TN = 32;

__global__ __launch_bounds__(512) void node_mlp1_mfma(
    const float* __restrict__ x0, const ushort* __restrict__ aggrb,
    const ushort* __restrict__ W3p, const float* __restrict__ b3,
    ushort* __restrict__ h)
{
    __shared__ __align__(16) ushort a_lds[TN * K3];  // 40 KB
    const int tid  = threadIdx.x;
    const int n0   = blockIdx.x * TN;
    const int ch   = blockIdx.y;
    const int lane = tid & 63;
    const int w    = tid >> 6;
    const int lr   = lane & 15;
    const int lg   = lane >> 4;

    #pragma unroll
    for (int i = 0; i < 5; ++i) {
        const int c    = i * 512 + tid;
        const int row  = c / 80;
        const int slot = c % 80;
        u16x8 u;
        if (slot < 16) {
            const float* sp = x0 + (size_t)(n0 + row) * D + slot * 8;
            const float4 va = ((const float4*)sp)[0];
            const float4 vb = ((const float4*)sp)[1];
            u[0] = f2bf(va.x); u[1] = f2bf(va.y); u[2] = f2bf(va.z); u[3] = f2bf(va.w);
            u[4] = f2bf(vb.x); u[5] = f2bf(vb.y); u[6] = f2bf(vb.z); u[7] = f2bf(vb.w);
        } else {
            u = *(const u16x8*)(aggrb + (size_t)(n0 + row) * H2 + (slot - 16) * 8);
        }
        *(u16x8*)((char*)a_lds + row * 1280 + swz(row, slot * 16)) = u;
    }
    __syncthreads();

    f32x4 acc[2][4];
    #pragma unroll
    for (int ntl = 0; ntl < 4; ++ntl) {
        const int colg = ch * 512 + (w * 4 + ntl) * 16 + lr;
        const float b = b3[colg];
        #pragma unroll
        for (int mt = 0; mt < 2; ++mt) acc[mt][ntl] = (f32x4){b, b, b, b};
    }
    for (int ks = 0; ks < 20; ++ks) {
        bf16x8 af[2];
        #pragma unroll
        for (int mt = 0; mt < 2; ++mt) {
            const int row = mt * 16 + lr;
            af[mt] = *(const bf16x8*)((const char*)a_lds + row * 1280 +
                                      swz(row, ks * 64 + lg * 16));
        }
        #pragma unroll
        for (int ntl = 0; ntl < 4; ++ntl) {
            const int nt = ch * 32 + w * 4 + ntl;
            const bf16x8 bf = *(const bf16x8*)(W3p +
                ((size_t)(nt * 20 + ks) * 64 + lane) * 8);
            #pragma unroll
            for (int mt = 0; mt < 2; ++mt)
                acc[mt][ntl] = mfma16(af[mt], bf, acc[mt][ntl]);
        }
    }
    #pragma unroll
    for (int mt = 0; mt < 2; ++mt)
        #pragma unroll
        for (int ntl = 0; ntl < 4; ++ntl) {
            const int colg = ch * 512 + (w * 4 + ntl) * 16 + lr;
            #pragma unroll
            for (int r = 0; r < 4; ++r) {
                const int row = n0 + mt * 16 + lg * 4 + r;
                h[(size_t)row * H3 + colg] = f2bf(leaky(acc[mt][ntl][r]));
            }
        }
}

// ---------------------------------------------------------------------------
// out = ((h @ W4 + b4)·BN + x0) / 2
// ---------------------------------------------------------------------------
__global__ __launch_bounds__(256) void node_mlp2_mfma(
    const ushort* __restrict__ h, const float* __restrict__ x0,
    const ushort* __restrict__ W4p, const float* __restrict__ b4,
    const float* __restrict__ gamma, const float* __restrict__ beta,
    const float* __restrict__ mean, const float* __restrict__ var,
    float* __restrict__ out)
{
    const int tid  = threadIdx.x;
    const int n0   = blockIdx.x * TN;
    const int lane = tid & 63;
    const int w    = tid >> 6;
    const int lr   = lane & 15;
    const int lg   = lane >> 4;

    f32x4 acc[2][2];
    #pragma unroll
    for (int ntl = 0; ntl < 2; ++ntl) {
        const float b = b4[(w * 2 + ntl) * 16 + lr];
        #pragma unroll
        for (int mt = 0; mt < 2; ++mt) acc[mt][ntl] = (f32x4){b, b, b, b};
    }
    for (int ks = 0; ks < 32; ++ks) {
        bf16x8 af[2];
        #pragma unroll
        for (int mt = 0; mt < 2; ++mt)
            af[mt] = *(const bf16x8*)(h + (size_t)(n0 + mt * 16 + lr) * H3 +
                                      ks * 32 + lg * 8);
        #pragma unroll
        for (int ntl = 0; ntl < 2; ++ntl) {
            const bf16x8 bf = *(const bf16x8*)(W4p +
                ((size_t)((w * 2 + ntl) * 32 + ks) * 64 + lane) * 8);
            #pragma unroll
            for (int mt = 0; mt < 2; ++mt)
                acc[mt][ntl] = mfma16(af[mt], bf, acc[mt][ntl]);
        }
    }
    #pragma unroll
    for (int ntl = 0; ntl < 2; ++ntl) {
        const int col = (w * 2 + ntl) * 16 + lr;
        const float sc = gamma[col] * rsqrtf(var[col] + 1e-5f);
        const float bo = beta[col] - mean[col] * sc;
        #pragma unroll
        for (int mt = 0; mt < 2; ++mt)
            #pragma unroll
            for (int r = 0; r < 4; ++r) {
                const int row = n0 + mt * 16 + lg * 4 + r;
                const float v = acc[mt][ntl][r] * sc + bo;
                out[(size_t)row * D + col] =
                    0.5f * (v + x0[(size_t)row * D + col]);
            }
    }
}

extern "C" void kernel_launch(void* const* d_in, const int* in_sizes, int n_in,
                              void* d_out, int out_size, void* d_ws, size_t ws_size,
                              hipStream_t stream)
{
    const float* x0    = (const float*)d_in[0];
    const int*   ei    = (const int*)d_in[1];
    const float* ea    = (const float*)d_in[2];
    const float* W1    = (const float*)d_in[3];
    const float* b1    = (const float*)d_in[4];
    const float* W2    = (const float*)d_in[5];
    const float* b2    = (const float*)d_in[6];
    const float* W3    = (const float*)d_in[7];
    const float* b3    = (const float*)d_in[8];
    const float* W4    = (const float*)d_in[9];
    const float* b4    = (const float*)d_in[10];
    const float* gamma = (const float*)d_in[11];
    const float* beta  = (const float*)d_in[12];
    const float* mean  = (const float*)d_in[13];
    const float* var   = (const float*)d_in[14];
    float* out = (float*)d_out;

    const int N = in_sizes[0] / D;   // 20000
    const int E = in_sizes[2] / D;   // 320000
    const int* src = ei;
    const int* dst = ei + E;

    // workspace (~355 MB):
    //   aggrb bf16[N*512]  20.5 MB
    //   m2    bf16[E*512] 327.7 MB  (h bf16[N*1024]=41MB aliases m2: mlp1
    //                                writes h AFTER aggregate consumed m2)
    //   sort ints + packed weights ~4.6 MB
    char* ws = (char*)d_ws;
    ushort* aggrb = (ushort*)ws;
    ushort* m2    = (ushort*)(ws + (size_t)N * H2 * 2);
    ushort* h     = m2;  // alias, see above
    char*   p2    = (char*)(m2 + (size_t)E * H2);
    int* cursor    = (int*)p2;           // N
    int* row_start = cursor + N;         // N+1
    int* se        = row_start + N + 1;  // E
    int* pe        = se + E;             // E
    ushort* W1p = (ushort*)(pe + E);
    ushort* W2p = W1p + (size_t)(D  / 32) * (H1 / 16) * 512;
    ushort* W3p = W2p + (size_t)(H1 / 32) * (H2 / 16) * 512;
    ushort* W4p = W3p + (size_t)(K3 / 32) * (H3 / 16) * 512;

    hipMemsetAsync(cursor, 0, (size_t)N * sizeof(int), stream);

    pack_all_weights<<<(118784 + 255) / 256, 256, 0, stream>>>(
        W1, W2, W3, W4, W1p, W2p, W3p, W4p);

    hist_kernel<<<(E + 255) / 256, 256, 0, stream>>>(dst, cursor, E);
    scan_kernel<<<1, 1024, 0, stream>>>(cursor, row_start, N);
    scatter_kernel<<<(E + 255) / 256, 256, 0, stream>>>(src, dst, cursor,
                                                        se, pe, E);

    edge_mlp_dense<<<E / TE, 512, 0, stream>>>(x0, ea, se, pe,
                                               W1p, b1, W2p, b2, m2);
    aggregate_kernel<<<N / 8, 512, 0, stream>>>(m2, row_start, aggrb);

    dim3 g1(N / TN, 2);
    node_mlp1_mfma<<<g1, 512, 0, stream>>>(x0, aggrb, W3p, b3, h);
    node_mlp2_mfma<<<N / TN, 256, 0, stream>>>(h, x0, W4p, b4, gamma, beta, mean, var, out);
}